// Round 1
// baseline (877.795 us; speedup 1.0000x reference)
//
#include <hip/hip_runtime.h>

// Problem constants
#define SQ 2048
#define BB 2
#define EE 1024
#define HH 16
#define DD 64
#define MM (SQ*BB)   // 4096 rows (s*B + b)

typedef _Float16 f16;
typedef _Float16 half8 __attribute__((ext_vector_type(8)));
typedef float f32x4 __attribute__((ext_vector_type(4)));

static __device__ __forceinline__ f32x4 mfma16(half8 a, half8 b, f32x4 c) {
    return __builtin_amdgcn_mfma_f32_16x16x32_f16(a, b, c, 0, 0, 0);
}

// ---------------- elementwise converts ----------------
__global__ void k_cvt(const float* __restrict__ src, f16* __restrict__ dst, int n) {
    int i = (blockIdx.x * blockDim.x + threadIdx.x) * 4;
    if (i < n) {
        float4 v = *(const float4*)(src + i);
        dst[i+0] = (f16)v.x; dst[i+1] = (f16)v.y;
        dst[i+2] = (f16)v.z; dst[i+3] = (f16)v.w;
    }
}

// o_w = mean + eps * exp(lgstd), stored fp16
__global__ void k_ow(const float* __restrict__ mean, const float* __restrict__ lgstd,
                     const float* __restrict__ eps, f16* __restrict__ dst, int n) {
    int i = (blockIdx.x * blockDim.x + threadIdx.x) * 4;
    if (i < n) {
        float4 m = *(const float4*)(mean + i);
        float4 l = *(const float4*)(lgstd + i);
        float4 e = *(const float4*)(eps + i);
        dst[i+0] = (f16)(m.x + e.x * expf(l.x));
        dst[i+1] = (f16)(m.y + e.y * expf(l.y));
        dst[i+2] = (f16)(m.z + e.z * expf(l.z));
        dst[i+3] = (f16)(m.w + e.w * expf(l.w));
    }
}

// ---------------- GEMM: C[M,N] = (A[M,K] @ W[N,K]^T + bias) * scale ----------------
// Both operands K-major ("bt" form): A-frag and B-frag loads are symmetric.
// 128x128 tile, BK=32, 4 waves each computing 64x64 (4x4 MFMA tiles).
// LDS stride 40 halfs (=80B, 5*16B): b128 frag reads land evenly on banks ((5m+q)%8 groups).
template<bool OUT16>
__global__ __launch_bounds__(256) void k_gemm_bt(
    const f16* __restrict__ A, const f16* __restrict__ W,
    const float* __restrict__ bias, float scale,
    void* __restrict__ Cout, int Kdim, int Ndim)
{
    __shared__ f16 As[128][40];
    __shared__ f16 Bs[128][40];
    int t = threadIdx.x;
    int lane = t & 63, wid = t >> 6;
    int quad = lane >> 4, m16 = lane & 15;
    int wm = wid >> 1, wn = wid & 1;
    int gm0 = blockIdx.x * 128, gn0 = blockIdx.y * 128;
    f32x4 acc[4][4] = {};
    for (int kt = 0; kt < Kdim; kt += 32) {
        for (int i = 0; i < 2; ++i) {
            int c = t + i * 256;
            int row = c >> 2, ch = c & 3;
            *(uint4*)&As[row][ch*8] = *(const uint4*)&A[(size_t)(gm0+row)*Kdim + kt + ch*8];
            *(uint4*)&Bs[row][ch*8] = *(const uint4*)&W[(size_t)(gn0+row)*Kdim + kt + ch*8];
        }
        __syncthreads();
        half8 af[4], bf[4];
        for (int i = 0; i < 4; ++i) af[i] = *(half8*)&As[wm*64 + i*16 + m16][quad*8];
        for (int j = 0; j < 4; ++j) bf[j] = *(half8*)&Bs[wn*64 + j*16 + m16][quad*8];
        for (int i = 0; i < 4; ++i)
            for (int j = 0; j < 4; ++j)
                acc[i][j] = mfma16(af[i], bf[j], acc[i][j]);
        __syncthreads();
    }
    // Epilogue. C/D layout: col = lane&15, row = quad*4 + reg (m89/m91-verified).
    for (int j = 0; j < 4; ++j) {
        int col = gn0 + wn*64 + j*16 + m16;
        float b = bias ? bias[col] : 0.0f;
        for (int i = 0; i < 4; ++i) {
            int row0 = gm0 + wm*64 + i*16 + quad*4;
            for (int r = 0; r < 4; ++r) {
                float v = (acc[i][j][r] + b) * scale;
                if (OUT16) ((f16*)Cout)[(size_t)(row0+r)*Ndim + col] = (f16)v;
                else       ((float*)Cout)[(size_t)(row0+r)*Ndim + col] = v;
            }
        }
    }
}

// ---------------- phase 1: softmax denominators ----------------
// No max-subtraction needed: |s| <~ 6 so sum(e^s) is safely in fp32 range.
// grid (q-tile64, h, b); each wg streams K_bh once, accumulates l per q row.
__global__ __launch_bounds__(256) void k_attn_l(
    const f16* __restrict__ Q16, const f16* __restrict__ K16,
    float* __restrict__ invl)
{
    __shared__ f16 Ks[128][72];     // 72-half stride: even bank spread for b128 reads
    __shared__ float red[4][64];
    int t = threadIdx.x, lane = t & 63, w = t >> 6;
    int quad = lane >> 4, m16 = lane & 15;
    int q0 = blockIdx.x * 64, h = blockIdx.y, b = blockIdx.z;

    half8 aq[4][2];
    for (int rt = 0; rt < 4; ++rt)
        for (int ks = 0; ks < 2; ++ks)
            aq[rt][ks] = *(const half8*)&Q16[(size_t)((q0 + rt*16 + m16)*BB + b)*EE + h*DD + ks*32 + quad*8];

    float lsum[4][4] = {};
    for (int kt = 0; kt < 16; ++kt) {
        for (int i = 0; i < 4; ++i) {
            int c = t + i * 256, row = c >> 3, ch = c & 7;
            *(uint4*)&Ks[row][ch*8] = *(const uint4*)&K16[(size_t)((kt*128 + row)*BB + b)*EE + h*DD + ch*8];
        }
        __syncthreads();
        for (int ct = 0; ct < 2; ++ct) {
            half8 bk0 = *(half8*)&Ks[w*32 + ct*16 + m16][quad*8];
            half8 bk1 = *(half8*)&Ks[w*32 + ct*16 + m16][32 + quad*8];
            for (int rt = 0; rt < 4; ++rt) {
                f32x4 s = {};
                s = mfma16(aq[rt][0], bk0, s);
                s = mfma16(aq[rt][1], bk1, s);
                for (int r = 0; r < 4; ++r) lsum[rt][r] += expf(s[r]);
            }
        }
        __syncthreads();
    }
    // reduce across the 16 column-lanes of each quad
    for (int rt = 0; rt < 4; ++rt)
        for (int r = 0; r < 4; ++r) {
            float v = lsum[rt][r];
            for (int d = 1; d < 16; d <<= 1) v += __shfl_xor(v, d, 64);
            lsum[rt][r] = v;
        }
    if (m16 == 0)
        for (int rt = 0; rt < 4; ++rt)
            for (int r = 0; r < 4; ++r)
                red[w][rt*16 + quad*4 + r] = lsum[rt][r];
    __syncthreads();
    if (t < 64) {
        float v = red[0][t] + red[1][t] + red[2][t] + red[3][t];
        invl[((size_t)b*HH + h)*SQ + q0 + t] = 1.0f / v;
    }
}

// ---------------- phase 2: probs, avg_attn, ctx ----------------
// grid (q-tile16, b). WG exclusively owns avg_attn[b, q0..q0+15, :] -> no atomics.
// ctx accumulators: 16 heads x f32x4 per lane (wave w owns d-cols w*16..w*16+15).
__global__ __launch_bounds__(256) void k_attn_main(
    const f16* __restrict__ Q16, const f16* __restrict__ K16, const f16* __restrict__ V16,
    const float* __restrict__ invl_g, f16* __restrict__ ctx16, float* __restrict__ avg_out)
{
    __shared__ f16 Ks[128][72];
    __shared__ f16 Vst[64][136];    // V transposed: [d][k], 136-half stride
    __shared__ f16 ps[16][136];     // probs of current head, [q][k]
    __shared__ float avg[16][132];  // per-k-tile head-sum
    __shared__ float invl[HH][16];
    int t = threadIdx.x, lane = t & 63, w = t >> 6;
    int quad = lane >> 4, m16 = lane & 15;
    int q0 = blockIdx.x * 16, b = blockIdx.y;

    { int hh = t >> 4, rr = t & 15;
      invl[hh][rr] = invl_g[((size_t)b*HH + hh)*SQ + q0 + rr]; }

    f32x4 ctxa[HH] = {};
    for (int kt = 0; kt < 16; ++kt) {
        __syncthreads();                       // prev kt's avg-write done
        for (int i = t; i < 16*132; i += 256) ((float*)avg)[i] = 0.f;
        for (int h = 0; h < HH; ++h) {
            __syncthreads();                   // (1) prev PV done / avg zero visible
            for (int i = 0; i < 4; ++i) {      // stage K tile [128 k][64 d]
                int c = t + i * 256, row = c >> 3, ch = c & 7;
                *(uint4*)&Ks[row][ch*8] = *(const uint4*)&K16[(size_t)((kt*128 + row)*BB + b)*EE + h*DD + ch*8];
            }
            for (int i = 0; i < 4; ++i) {      // stage V transposed [64 d][128 k]
                int c = t + i * 256, kk = c & 127, dc = c >> 7;
                uint4 raw = *(const uint4*)&V16[(size_t)((kt*128 + kk)*BB + b)*EE + h*DD + dc*8];
                const f16* vv = (const f16*)&raw;
                for (int j = 0; j < 8; ++j) Vst[dc*8 + j][kk] = vv[j];
            }
            __syncthreads();                   // (2)
            // scores: Q(16x64) x K^T(64x128), wave w takes cols w*32..w*32+31
            half8 aq0 = *(const half8*)&Q16[(size_t)((q0 + m16)*BB + b)*EE + h*DD + quad*8];
            half8 aq1 = *(const half8*)&Q16[(size_t)((q0 + m16)*BB + b)*EE + h*DD + 32 + quad*8];
            for (int ct = 0; ct < 2; ++ct) {
                half8 bk0 = *(half8*)&Ks[w*32 + ct*16 + m16][quad*8];
                half8 bk1 = *(half8*)&Ks[w*32 + ct*16 + m16][32 + quad*8];
                f32x4 s = {};
                s = mfma16(aq0, bk0, s);
                s = mfma16(aq1, bk1, s);
                for (int r = 0; r < 4; ++r) {
                    int row = quad*4 + r;
                    float p = expf(s[r]) * invl[h][row];
                    ps[row][w*32 + ct*16 + m16] = (f16)p;
                    avg[row][w*32 + ct*16 + m16] += p;   // lane-exclusive slot: no race
                }
            }
            __syncthreads();                   // (3) ps complete
            // PV: ctx[16 x 64] += p(16x128) @ V(128x64); wave w owns d-cols w*16..+15
            f32x4 c4 = ctxa[h];
            for (int ks = 0; ks < 4; ++ks) {
                half8 ap = *(half8*)&ps[m16][ks*32 + quad*8];
                half8 bv = *(half8*)&Vst[w*16 + m16][ks*32 + quad*8];
                c4 = mfma16(ap, bv, c4);
            }
            ctxa[h] = c4;
        }
        // write avg_attn tile (owned rows; all adds completed before barrier (3))
        for (int i = t; i < 16*128; i += 256) {
            int row = i >> 7, col = i & 127;
            avg_out[((size_t)b*SQ + q0 + row)*SQ + kt*128 + col] = avg[row][col] * (1.0f/HH);
        }
    }
    // write ctx (fp16) in [s*B+b][E] layout for the output GEMM
    for (int h = 0; h < HH; ++h)
        for (int r = 0; r < 4; ++r) {
            int srow = q0 + quad*4 + r;
            ctx16[(size_t)(srow*BB + b)*EE + h*DD + w*16 + m16] = (f16)ctxa[h][r];
        }
}

// ---------------- launch ----------------
extern "C" void kernel_launch(void* const* d_in, const int* in_sizes, int n_in,
                              void* d_out, int out_size, void* d_ws, size_t ws_size,
                              hipStream_t stream) {
    const float* query    = (const float*)d_in[0];
    const float* key      = (const float*)d_in[1];
    const float* value    = (const float*)d_in[2];
    const float* q_w      = (const float*)d_in[3];
    const float* q_b      = (const float*)d_in[4];
    const float* k_w      = (const float*)d_in[5];
    const float* k_b      = (const float*)d_in[6];
    const float* v_w      = (const float*)d_in[7];
    const float* v_b      = (const float*)d_in[8];
    const float* o_w_mean = (const float*)d_in[9];
    const float* o_w_lgstd= (const float*)d_in[10];
    const float* eps      = (const float*)d_in[11];
    float* out = (float*)d_out;                 // [S,B,E] fp32
    float* avg = out + (size_t)MM * EE;         // [B,S,S] fp32

    // ws layout (fp16 unless noted); total ~64.5 MB
    f16* qw16  = (f16*)d_ws;
    f16* kw16  = qw16 + (size_t)EE*EE;
    f16* vw16  = kw16 + (size_t)EE*EE;
    f16* ow16  = vw16 + (size_t)EE*EE;
    f16* xq16  = ow16 + (size_t)EE*EE;
    f16* xk16  = xq16 + (size_t)MM*EE;
    f16* xv16  = xk16 + (size_t)MM*EE;
    f16* Q16   = xv16 + (size_t)MM*EE;
    f16* K16   = Q16  + (size_t)MM*EE;
    f16* V16   = K16  + (size_t)MM*EE;
    f16* ctx16 = V16  + (size_t)MM*EE;
    float* invl = (float*)(ctx16 + (size_t)MM*EE);  // B*H*S fp32

    const int EW = EE*EE;       // 1M
    const int XW = MM*EE;       // 4M
    k_cvt<<<EW/4/256, 256, 0, stream>>>(q_w, qw16, EW);
    k_cvt<<<EW/4/256, 256, 0, stream>>>(k_w, kw16, EW);
    k_cvt<<<EW/4/256, 256, 0, stream>>>(v_w, vw16, EW);
    k_ow <<<EW/4/256, 256, 0, stream>>>(o_w_mean, o_w_lgstd, eps, ow16, EW);
    k_cvt<<<XW/4/256, 256, 0, stream>>>(query, xq16, XW);
    k_cvt<<<XW/4/256, 256, 0, stream>>>(key,   xk16, XW);
    k_cvt<<<XW/4/256, 256, 0, stream>>>(value, xv16, XW);

    dim3 gg(MM/128, EE/128);
    k_gemm_bt<true><<<gg, 256, 0, stream>>>(xq16, qw16, q_b, 0.125f, Q16, EE, EE);
    k_gemm_bt<true><<<gg, 256, 0, stream>>>(xk16, kw16, k_b, 1.0f,   K16, EE, EE);
    k_gemm_bt<true><<<gg, 256, 0, stream>>>(xv16, vw16, v_b, 1.0f,   V16, EE, EE);

    k_attn_l   <<<dim3(SQ/64, HH, BB), 256, 0, stream>>>(Q16, K16, invl);
    k_attn_main<<<dim3(SQ/16, BB),     256, 0, stream>>>(Q16, K16, V16, invl, ctx16, avg);

    k_gemm_bt<false><<<gg, 256, 0, stream>>>(ctx16, ow16, nullptr, 1.0f, out, EE, EE);
}

// Round 2
// 426.499 us; speedup vs baseline: 2.0581x; 2.0581x over previous
//
#include <hip/hip_runtime.h>

#define SQ 2048
#define BB 2
#define EE 1024
#define HH 16
#define DD 64
#define MM (SQ*BB)          // 4096 composite rows (s*B + b)
#define NSLICE 4
#define KSLICE (SQ/NSLICE)  // 512 k per attn_main wg
#define KT_IN (KSLICE/128)  // 4 kt tiles of 128
#define LOG2E 1.44269504f

typedef _Float16 f16;
typedef _Float16 half8 __attribute__((ext_vector_type(8)));
typedef _Float16 half4 __attribute__((ext_vector_type(4)));
typedef float f32x4 __attribute__((ext_vector_type(4)));

static __device__ __forceinline__ f32x4 mfma16(half8 a, half8 b, f32x4 c) {
    return __builtin_amdgcn_mfma_f32_16x16x32_f16(a, b, c, 0, 0, 0);
}

// async global->LDS, 16B per lane. LDS dst must be base + lane*16 contiguous.
static __device__ __forceinline__ void gload16(const f16* g, f16* l) {
    __builtin_amdgcn_global_load_lds(
        (const __attribute__((address_space(1))) unsigned int*)g,
        (__attribute__((address_space(3))) unsigned int*)l, 16, 0, 0);
}

// ---------------- fused elementwise converts ----------------
__global__ void k_elem(const float* __restrict__ q_w, const float* __restrict__ k_w,
                       const float* __restrict__ v_w, const float* __restrict__ query,
                       const float* __restrict__ key, const float* __restrict__ value,
                       const float* __restrict__ owm, const float* __restrict__ owl,
                       const float* __restrict__ eps,
                       f16* qw16, f16* kw16, f16* vw16,
                       f16* xq16, f16* xk16, f16* xv16, f16* ow16)
{
    int y = blockIdx.y;
    size_t i = ((size_t)blockIdx.x * 256 + threadIdx.x) * 4;
    if (y < 3) {
        if (i >= (size_t)EE*EE) return;
        const float* s = (y==0) ? q_w : (y==1) ? k_w : v_w;
        f16* d = (y==0) ? qw16 : (y==1) ? kw16 : vw16;
        float4 v = *(const float4*)&s[i];
        half4 o = {(f16)v.x, (f16)v.y, (f16)v.z, (f16)v.w};
        *(half4*)&d[i] = o;
    } else if (y < 6) {
        const float* s = (y==3) ? query : (y==4) ? key : value;
        f16* d = (y==3) ? xq16 : (y==4) ? xk16 : xv16;
        float4 v = *(const float4*)&s[i];
        half4 o = {(f16)v.x, (f16)v.y, (f16)v.z, (f16)v.w};
        *(half4*)&d[i] = o;
    } else {
        if (i >= (size_t)EE*EE) return;
        float4 m = *(const float4*)&owm[i];
        float4 l = *(const float4*)&owl[i];
        float4 e = *(const float4*)&eps[i];
        half4 o = {(f16)(m.x + e.x * __expf(l.x)), (f16)(m.y + e.y * __expf(l.y)),
                   (f16)(m.z + e.z * __expf(l.z)), (f16)(m.w + e.w * __expf(l.w))};
        *(half4*)&ow16[i] = o;
    }
}

// ---------------- GEMM: C[M,N] = (A[M,K] @ W[N,K]^T + bias) * scale ----------------
// 128x64 tile, BK=32, 4 waves each 64x32 (4x2 MFMA tiles). global_load_lds staging,
// unpadded LDS with XOR-of-(row&3) chunk swizzle for bank spread.
template<bool F32OUT, bool VT>
__global__ __launch_bounds__(256) void k_gemm(
    const f16* __restrict__ A, const f16* __restrict__ W,
    const float* __restrict__ bias, float scale, void* __restrict__ out)
{
    __shared__ f16 As[128*32];
    __shared__ f16 Bs[64*32];
    int t = threadIdx.x, lane = t & 63, w = t >> 6;
    int quad = lane >> 4, m16 = lane & 15;
    int wm = w >> 1, wn = w & 1;
    int gm0 = blockIdx.x * 128, gn0 = blockIdx.y * 64;
    int arow = lane >> 2, apch = lane & 3;
    f32x4 acc[4][2] = {};
    for (int kt = 0; kt < EE; kt += 32) {
        #pragma unroll
        for (int j = 0; j < 2; ++j) {
            int row = w*32 + j*16 + arow;
            int lch = apch ^ (row & 3);
            gload16(&A[(size_t)(gm0+row)*EE + kt + lch*8], &As[row*32 + apch*8]);
        }
        {
            int row = w*16 + arow;
            int lch = apch ^ (row & 3);
            gload16(&W[(size_t)(gn0+row)*EE + kt + lch*8], &Bs[row*32 + apch*8]);
        }
        __syncthreads();
        int cs = (quad ^ (m16 & 3)) * 8;
        half8 af[4], bf[2];
        #pragma unroll
        for (int i = 0; i < 4; ++i) af[i] = *(half8*)&As[(wm*64 + i*16 + m16)*32 + cs];
        #pragma unroll
        for (int j = 0; j < 2; ++j) bf[j] = *(half8*)&Bs[(wn*32 + j*16 + m16)*32 + cs];
        #pragma unroll
        for (int i = 0; i < 4; ++i)
            #pragma unroll
            for (int j = 0; j < 2; ++j)
                acc[i][j] = mfma16(af[i], bf[j], acc[i][j]);
        __syncthreads();
    }
    // C/D layout: col = lane&15, row = quad*4 + reg
    #pragma unroll
    for (int j = 0; j < 2; ++j) {
        int col = gn0 + wn*32 + j*16 + m16;
        float bb = bias ? bias[col] : 0.0f;
        #pragma unroll
        for (int i = 0; i < 4; ++i) {
            int r0 = gm0 + wm*64 + i*16 + quad*4;
            #pragma unroll
            for (int r = 0; r < 4; ++r) {
                float v = (acc[i][j][r] + bb) * scale;
                int m = r0 + r;
                if (F32OUT)      ((float*)out)[(size_t)m*EE + col] = v;
                else if (VT)     ((f16*)out)[((size_t)(m & 1)*EE + col)*SQ + (m >> 1)] = (f16)v;
                else             ((f16*)out)[(size_t)m*EE + col] = (f16)v;
            }
        }
    }
}

// ---------------- phase 1: lse2 = log2(sum_k exp(s)) per (b,h,q) ----------------
__global__ __launch_bounds__(256) void k_attn_l(
    const f16* __restrict__ Q16, const f16* __restrict__ K16,
    float* __restrict__ lse2)
{
    __shared__ f16 Ks[128][72];
    __shared__ float red[4][64];
    int t = threadIdx.x, lane = t & 63, w = t >> 6;
    int quad = lane >> 4, m16 = lane & 15;
    int q0 = blockIdx.x * 64, h = blockIdx.y, b = blockIdx.z;

    half8 aq[4][2];
    for (int rt = 0; rt < 4; ++rt)
        for (int ks = 0; ks < 2; ++ks)
            aq[rt][ks] = *(const half8*)&Q16[(size_t)((q0 + rt*16 + m16)*BB + b)*EE + h*DD + ks*32 + quad*8];

    float lsum[4][4] = {};
    for (int kt = 0; kt < 16; ++kt) {
        for (int i = 0; i < 4; ++i) {
            int c = t + i * 256, row = c >> 3, ch = c & 7;
            *(uint4*)&Ks[row][ch*8] = *(const uint4*)&K16[(size_t)((kt*128 + row)*BB + b)*EE + h*DD + ch*8];
        }
        __syncthreads();
        for (int ct = 0; ct < 2; ++ct) {
            half8 bk0 = *(half8*)&Ks[w*32 + ct*16 + m16][quad*8];
            half8 bk1 = *(half8*)&Ks[w*32 + ct*16 + m16][32 + quad*8];
            for (int rt = 0; rt < 4; ++rt) {
                f32x4 s = {};
                s = mfma16(aq[rt][0], bk0, s);
                s = mfma16(aq[rt][1], bk1, s);
                #pragma unroll
                for (int r = 0; r < 4; ++r)
                    lsum[rt][r] += __builtin_amdgcn_exp2f(s[r] * LOG2E);
            }
        }
        __syncthreads();
    }
    for (int rt = 0; rt < 4; ++rt)
        for (int r = 0; r < 4; ++r) {
            float v = lsum[rt][r];
            for (int d = 1; d < 16; d <<= 1) v += __shfl_xor(v, d, 64);
            lsum[rt][r] = v;
        }
    if (m16 == 0)
        for (int rt = 0; rt < 4; ++rt)
            for (int r = 0; r < 4; ++r)
                red[w][rt*16 + quad*4 + r] = lsum[rt][r];
    __syncthreads();
    if (t < 64) {
        float v = red[0][t] + red[1][t] + red[2][t] + red[3][t];
        lse2[((size_t)b*HH + h)*SQ + q0 + t] = log2f(v);
    }
}

// ---------------- phase 2: probs, avg_attn (regs), ctx partials ----------------
// grid (SQ/32, NSLICE, B) = (64,4,2) = 512 wgs, 2/CU. wg owns avg[b, q0..+31, ks0..+511].
__global__ __launch_bounds__(256, 2) void k_attn_main(
    const f16* __restrict__ Q16, const f16* __restrict__ K16, const f16* __restrict__ Vt16,
    const float* __restrict__ lse2, float* __restrict__ ctxp, float* __restrict__ avg_out)
{
    __shared__ f16 Ks[128*64];    // [k 128][d 64], chunk-swizzled
    __shared__ f16 Vst[64*128];   // [d 64][k 128], chunk-swizzled
    __shared__ f16 ps[32][136];   // probs [q][k]
    __shared__ float csh[HH][32]; // log2 denominators
    int t = threadIdx.x, lane = t & 63, w = t >> 6;
    int quad = lane >> 4, m16 = lane & 15;
    int q0 = blockIdx.x * 32, sl = blockIdx.y, b = blockIdx.z;
    int ks0 = sl * KSLICE;

    for (int i = t; i < HH*32; i += 256) {
        int hh = i >> 5, qq = i & 31;
        csh[hh][qq] = lse2[((size_t)b*HH + hh)*SQ + q0 + qq];
    }

    float avg_r[KT_IN][16] = {};   // [kt][rt*8 + ct*4 + r], lane-exclusive (q,k) slots

    for (int hg = 0; hg < 2; ++hg) {
        f32x4 acc[8][2] = {};
        for (int h8 = 0; h8 < 8; ++h8) {
            int h = hg*8 + h8;
            half8 aq[2][2];
            #pragma unroll
            for (int rt = 0; rt < 2; ++rt)
                #pragma unroll
                for (int kk = 0; kk < 2; ++kk)
                    aq[rt][kk] = *(const half8*)&Q16[(size_t)((q0 + rt*16 + m16)*BB + b)*EE + h*DD + kk*32 + quad*8];
            for (int kt = 0; kt < KT_IN; ++kt) {
                __syncthreads();   // (C) prior PV reads of Ks/Vst/ps complete
                // stage K tile [128][64] via async 16B (4 instrs/wave)
                #pragma unroll
                for (int j = 0; j < 4; ++j) {
                    int r = w*32 + j*8 + (lane >> 3);
                    int pch = lane & 7, lch = pch ^ (r & 7);
                    gload16(&K16[(size_t)((ks0 + kt*128 + r)*BB + b)*EE + h*DD + lch*8],
                            &Ks[r*64 + pch*8]);
                }
                // stage V^T tile [64][128] via async 16B (4 instrs/wave)
                #pragma unroll
                for (int j = 0; j < 4; ++j) {
                    int d = w*16 + j*4 + (lane >> 4);
                    int pch = lane & 15, lch = pch ^ (d & 15);
                    gload16(&Vt16[((size_t)b*EE + h*DD + d)*SQ + ks0 + kt*128 + lch*8],
                            &Vst[d*128 + pch*8]);
                }
                __syncthreads();   // (A) staging drained
                // QK^T 32x128 + exp2 + ps + avg
                #pragma unroll
                for (int ct = 0; ct < 2; ++ct) {
                    int rk = w*32 + ct*16 + m16;
                    half8 bk0 = *(half8*)&Ks[rk*64 + ((quad     ^ (rk & 7)))*8];
                    half8 bk1 = *(half8*)&Ks[rk*64 + (((4+quad) ^ (rk & 7)))*8];
                    #pragma unroll
                    for (int rt = 0; rt < 2; ++rt) {
                        f32x4 s = {};
                        s = mfma16(aq[rt][0], bk0, s);
                        s = mfma16(aq[rt][1], bk1, s);
                        #pragma unroll
                        for (int r = 0; r < 4; ++r) {
                            int qrow = rt*16 + quad*4 + r;
                            float p = __builtin_amdgcn_exp2f(s[r] * LOG2E - csh[h][qrow]);
                            avg_r[kt][rt*8 + ct*4 + r] += p;
                            ps[qrow][w*32 + ct*16 + m16] = (f16)p;
                        }
                    }
                }
                __syncthreads();   // (B) ps complete
                // PV: ctx[32q x 64d] += p @ V; wave w owns d = w*16..+15
                #pragma unroll
                for (int rt = 0; rt < 2; ++rt) {
                    f32x4 c4 = acc[h8][rt];
                    #pragma unroll
                    for (int ks = 0; ks < 4; ++ks) {
                        half8 ap = *(half8*)&ps[rt*16 + m16][ks*32 + quad*8];
                        int d = w*16 + m16;
                        int pch = (ks*4 + quad) ^ (d & 15);
                        half8 bv = *(half8*)&Vst[d*128 + pch*8];
                        c4 = mfma16(ap, bv, c4);
                    }
                    acc[h8][rt] = c4;
                }
            }
        }
        // flush ctx partials for this head group (fp32)
        #pragma unroll
        for (int h8 = 0; h8 < 8; ++h8)
            #pragma unroll
            for (int rt = 0; rt < 2; ++rt)
                #pragma unroll
                for (int r = 0; r < 4; ++r) {
                    int q = q0 + rt*16 + quad*4 + r;
                    int d = w*16 + m16;
                    ctxp[(size_t)sl*MM*EE + ((size_t)q*BB + b)*EE + (hg*8 + h8)*DD + d] = acc[h8][rt][r];
                }
    }
    // write owned avg tile
    #pragma unroll
    for (int kt = 0; kt < KT_IN; ++kt)
        #pragma unroll
        for (int rt = 0; rt < 2; ++rt)
            #pragma unroll
            for (int ct = 0; ct < 2; ++ct)
                #pragma unroll
                for (int r = 0; r < 4; ++r) {
                    int q = q0 + rt*16 + quad*4 + r;
                    int k = ks0 + kt*128 + w*32 + ct*16 + m16;
                    avg_out[((size_t)b*SQ + q)*SQ + k] = avg_r[kt][rt*8 + ct*4 + r] * (1.0f/HH);
                }
}

// ---------------- ctx partial reduction: fp32 x NSLICE -> f16 ----------------
__global__ void k_ctx_red(const float* __restrict__ ctxp, f16* __restrict__ ctx16) {
    size_t i = ((size_t)blockIdx.x * 256 + threadIdx.x) * 4;
    float4 s = *(const float4*)&ctxp[i];
    #pragma unroll
    for (int sl = 1; sl < NSLICE; ++sl) {
        float4 v = *(const float4*)&ctxp[(size_t)sl*MM*EE + i];
        s.x += v.x; s.y += v.y; s.z += v.z; s.w += v.w;
    }
    half4 o = {(f16)s.x, (f16)s.y, (f16)s.z, (f16)s.w};
    *(half4*)&ctx16[i] = o;
}

// ---------------- launch ----------------
extern "C" void kernel_launch(void* const* d_in, const int* in_sizes, int n_in,
                              void* d_out, int out_size, void* d_ws, size_t ws_size,
                              hipStream_t stream) {
    const float* query    = (const float*)d_in[0];
    const float* key      = (const float*)d_in[1];
    const float* value    = (const float*)d_in[2];
    const float* q_w      = (const float*)d_in[3];
    const float* q_b      = (const float*)d_in[4];
    const float* k_w      = (const float*)d_in[5];
    const float* k_b      = (const float*)d_in[6];
    const float* v_w      = (const float*)d_in[7];
    const float* v_b      = (const float*)d_in[8];
    const float* o_w_mean = (const float*)d_in[9];
    const float* o_w_lgstd= (const float*)d_in[10];
    const float* eps      = (const float*)d_in[11];
    float* out = (float*)d_out;                  // [S,B,E] fp32
    float* avg = out + (size_t)MM * EE;          // [B,S,S] fp32

    const size_t EWN = (size_t)EE*EE;   // 1M
    const size_t XWN = (size_t)MM*EE;   // 4M
    f16* qw16  = (f16*)d_ws;
    f16* kw16  = qw16 + EWN;
    f16* vw16  = kw16 + EWN;
    f16* ow16  = vw16 + EWN;
    f16* Q16   = ow16 + EWN;
    f16* K16   = Q16  + XWN;
    f16* Vt16  = K16  + XWN;
    f16* ctx16 = Vt16 + XWN;
    float* lse2 = (float*)(ctx16 + XWN);             // B*H*S fp32
    f16* xq16  = (f16*)(lse2 + (size_t)BB*HH*SQ);
    f16* xk16  = xq16 + XWN;
    f16* xv16  = xk16 + XWN;
    // ctxp aliases xq/xk/xv (dead after projections) and extends beyond: NSLICE*16MB
    float* ctxp = (float*)xq16;

    k_elem<<<dim3(XWN/1024, 7), 256, 0, stream>>>(q_w, k_w, v_w, query, key, value,
        o_w_mean, o_w_lgstd, eps, qw16, kw16, vw16, xq16, xk16, xv16, ow16);

    dim3 gg(MM/128, EE/64);
    k_gemm<false,false><<<gg, 256, 0, stream>>>(xq16, qw16, q_b, 0.125f, Q16);
    k_gemm<false,false><<<gg, 256, 0, stream>>>(xk16, kw16, k_b, 1.0f,   K16);
    k_gemm<false,true ><<<gg, 256, 0, stream>>>(xv16, vw16, v_b, 1.0f,   Vt16);

    k_attn_l   <<<dim3(SQ/64, HH, BB), 256, 0, stream>>>(Q16, K16, lse2);
    k_attn_main<<<dim3(SQ/32, NSLICE, BB), 256, 0, stream>>>(Q16, K16, Vt16, lse2, ctxp, avg);
    k_ctx_red  <<<XWN/1024, 256, 0, stream>>>(ctxp, ctx16);

    k_gemm<true,false><<<gg, 256, 0, stream>>>(ctx16, ow16, nullptr, 1.0f, out);
}

// Round 3
// 392.442 us; speedup vs baseline: 2.2367x; 1.0868x over previous
//
#include <hip/hip_runtime.h>

#define SQ 2048
#define BB 2
#define EE 1024
#define HH 16
#define DD 64
#define MM (SQ*BB)          // 4096 composite rows (s*B + b)
#define NSLICE 4
#define KSLICE (SQ/NSLICE)  // 512 k per attn_main wg
#define KT_IN (KSLICE/128)  // 4 kt tiles of 128
#define LOG2E 1.44269504f

typedef _Float16 f16;
typedef _Float16 half8 __attribute__((ext_vector_type(8)));
typedef _Float16 half4 __attribute__((ext_vector_type(4)));
typedef float f32x4 __attribute__((ext_vector_type(4)));

static __device__ __forceinline__ f32x4 mfma16(half8 a, half8 b, f32x4 c) {
    return __builtin_amdgcn_mfma_f32_16x16x32_f16(a, b, c, 0, 0, 0);
}

// async global->LDS, 16B per lane (GEMM staging only)
static __device__ __forceinline__ void gload16(const f16* g, f16* l) {
    __builtin_amdgcn_global_load_lds(
        (const __attribute__((address_space(1))) unsigned int*)g,
        (__attribute__((address_space(3))) unsigned int*)l, 16, 0, 0);
}

// ---------------- fused elementwise converts ----------------
__global__ void k_elem(const float* __restrict__ q_w, const float* __restrict__ k_w,
                       const float* __restrict__ v_w, const float* __restrict__ query,
                       const float* __restrict__ key, const float* __restrict__ value,
                       const float* __restrict__ owm, const float* __restrict__ owl,
                       const float* __restrict__ eps,
                       f16* qw16, f16* kw16, f16* vw16,
                       f16* xq16, f16* xk16, f16* xv16, f16* ow16)
{
    int y = blockIdx.y;
    size_t i = ((size_t)blockIdx.x * 256 + threadIdx.x) * 4;
    if (y < 3) {
        if (i >= (size_t)EE*EE) return;
        const float* s = (y==0) ? q_w : (y==1) ? k_w : v_w;
        f16* d = (y==0) ? qw16 : (y==1) ? kw16 : vw16;
        float4 v = *(const float4*)&s[i];
        half4 o = {(f16)v.x, (f16)v.y, (f16)v.z, (f16)v.w};
        *(half4*)&d[i] = o;
    } else if (y < 6) {
        const float* s = (y==3) ? query : (y==4) ? key : value;
        f16* d = (y==3) ? xq16 : (y==4) ? xk16 : xv16;
        float4 v = *(const float4*)&s[i];
        half4 o = {(f16)v.x, (f16)v.y, (f16)v.z, (f16)v.w};
        *(half4*)&d[i] = o;
    } else {
        if (i >= (size_t)EE*EE) return;
        float4 m = *(const float4*)&owm[i];
        float4 l = *(const float4*)&owl[i];
        float4 e = *(const float4*)&eps[i];
        half4 o = {(f16)(m.x + e.x * __expf(l.x)), (f16)(m.y + e.y * __expf(l.y)),
                   (f16)(m.z + e.z * __expf(l.z)), (f16)(m.w + e.w * __expf(l.w))};
        *(half4*)&ow16[i] = o;
    }
}

// ---------------- GEMM body: C[M,N] = (A[M,K] @ W[N,K]^T + bias) * scale ----------------
// 128x64 tile, BK=32. mode: 0 = f16 row-major, 1 = f16 V-transposed [b][d][s], 2 = f32.
__device__ __forceinline__ void gemm_body(
    const f16* __restrict__ A, const f16* __restrict__ W,
    const float* __restrict__ bias, float scale, void* __restrict__ out, int mode)
{
    __shared__ f16 As[128*32];
    __shared__ f16 Bs[64*32];
    int t = threadIdx.x, lane = t & 63, w = t >> 6;
    int quad = lane >> 4, m16 = lane & 15;
    int wm = w >> 1, wn = w & 1;
    int gm0 = blockIdx.x * 128, gn0 = blockIdx.y * 64;
    int arow = lane >> 2, apch = lane & 3;
    f32x4 acc[4][2] = {};
    for (int kt = 0; kt < EE; kt += 32) {
        #pragma unroll
        for (int j = 0; j < 2; ++j) {
            int row = w*32 + j*16 + arow;
            int lch = apch ^ (row & 3);
            gload16(&A[(size_t)(gm0+row)*EE + kt + lch*8], &As[row*32 + apch*8]);
        }
        {
            int row = w*16 + arow;
            int lch = apch ^ (row & 3);
            gload16(&W[(size_t)(gn0+row)*EE + kt + lch*8], &Bs[row*32 + apch*8]);
        }
        __syncthreads();
        int cs = (quad ^ (m16 & 3)) * 8;
        half8 af[4], bf[2];
        #pragma unroll
        for (int i = 0; i < 4; ++i) af[i] = *(half8*)&As[(wm*64 + i*16 + m16)*32 + cs];
        #pragma unroll
        for (int j = 0; j < 2; ++j) bf[j] = *(half8*)&Bs[(wn*32 + j*16 + m16)*32 + cs];
        #pragma unroll
        for (int i = 0; i < 4; ++i)
            #pragma unroll
            for (int j = 0; j < 2; ++j)
                acc[i][j] = mfma16(af[i], bf[j], acc[i][j]);
        __syncthreads();
    }
    #pragma unroll
    for (int j = 0; j < 2; ++j) {
        int col = gn0 + wn*32 + j*16 + m16;
        float bb = bias ? bias[col] : 0.0f;
        #pragma unroll
        for (int i = 0; i < 4; ++i) {
            int r0 = gm0 + wm*64 + i*16 + quad*4;
            #pragma unroll
            for (int r = 0; r < 4; ++r) {
                float v = (acc[i][j][r] + bb) * scale;
                int m = r0 + r;
                if (mode == 2)      ((float*)out)[(size_t)m*EE + col] = v;
                else if (mode == 1) ((f16*)out)[((size_t)(m & 1)*EE + col)*SQ + (m >> 1)] = (f16)v;
                else                ((f16*)out)[(size_t)m*EE + col] = (f16)v;
            }
        }
    }
}

__global__ __launch_bounds__(256) void k_gemm_qkv(
    const f16* xq, const f16* qw, const float* qb,
    const f16* xk, const f16* kw, const float* kb,
    const f16* xv, const f16* vw, const float* vb,
    f16* Q16, f16* K16, f16* Vt16)
{
    int z = blockIdx.z;
    const f16* A = (z==0) ? xq : (z==1) ? xk : xv;
    const f16* W = (z==0) ? qw : (z==1) ? kw : vw;
    const float* bi = (z==0) ? qb : (z==1) ? kb : vb;
    float sc = (z==0) ? 0.125f * LOG2E : 1.0f;   // fold log2e into Q
    void* o = (z==0) ? (void*)Q16 : (z==1) ? (void*)K16 : (void*)Vt16;
    gemm_body(A, W, bi, sc, o, (z==2) ? 1 : 0);
}

__global__ __launch_bounds__(256) void k_gemm_o(const f16* A, const f16* W, float* out)
{
    gemm_body(A, W, nullptr, 1.0f, out, 2);
}

// ---------------- phase 1: lse2[b,h,q] = log2(sum_k 2^s2) ----------------
// No LDS staging, no in-loop barriers: wave w owns k-cols w*32..+31 of each 128-k tile.
__global__ __launch_bounds__(256, 4) void k_attn_l(
    const f16* __restrict__ Q16, const f16* __restrict__ K16, float* __restrict__ lse2)
{
    __shared__ float red[4][64];
    const int t = threadIdx.x, lane = t & 63, w = t >> 6;
    const int quad = lane >> 4, m16 = lane & 15;
    const int q0 = blockIdx.x * 64, h = blockIdx.y, b = blockIdx.z;

    half8 bq[4][2];
    #pragma unroll
    for (int nt = 0; nt < 4; ++nt)
        #pragma unroll
        for (int dk = 0; dk < 2; ++dk)
            bq[nt][dk] = *(const half8*)&Q16[(size_t)((q0 + nt*16 + m16)*BB + b)*EE + h*DD + dk*32 + quad*8];

    float lsum[4] = {};
    for (int kt = 0; kt < 16; ++kt) {
        half8 ak[2][2];
        #pragma unroll
        for (int mt = 0; mt < 2; ++mt)
            #pragma unroll
            for (int dk = 0; dk < 2; ++dk)
                ak[mt][dk] = *(const half8*)&K16[(size_t)((kt*128 + w*32 + mt*16 + m16)*BB + b)*EE + h*DD + dk*32 + quad*8];
        #pragma unroll
        for (int mt = 0; mt < 2; ++mt)
            #pragma unroll
            for (int nt = 0; nt < 4; ++nt) {
                f32x4 s = {};
                s = mfma16(ak[mt][0], bq[nt][0], s);   // S^T: rows k, cols q
                s = mfma16(ak[mt][1], bq[nt][1], s);
                lsum[nt] += __builtin_amdgcn_exp2f(s[0]) + __builtin_amdgcn_exp2f(s[1])
                          + __builtin_amdgcn_exp2f(s[2]) + __builtin_amdgcn_exp2f(s[3]);
            }
    }
    #pragma unroll
    for (int nt = 0; nt < 4; ++nt) {
        float v = lsum[nt];
        v += __shfl_xor(v, 16, 64);
        v += __shfl_xor(v, 32, 64);
        lsum[nt] = v;
    }
    if (quad == 0)
        #pragma unroll
        for (int nt = 0; nt < 4; ++nt) red[w][nt*16 + m16] = lsum[nt];
    __syncthreads();
    if (t < 64) {
        float v = red[0][t] + red[1][t] + red[2][t] + red[3][t];
        lse2[((size_t)b*HH + h)*SQ + q0 + t] = __log2f(v);
    }
}

// ---------------- phase 2: probs, avg_attn (regs), ctx partials ----------------
// grid (SQ/32, NSLICE, B) = 512. K/V frags direct from global (wave-exclusive rows/cols),
// software-pipelined. S^T layout -> ps writes are ds_write_b64. Double-buffered ps,
// ONE barrier per (h,kt) round.
__global__ __launch_bounds__(256, 2) void k_attn_main(
    const f16* __restrict__ Q16, const f16* __restrict__ K16, const f16* __restrict__ Vt16,
    const float* __restrict__ lse2, float* __restrict__ ctxp, float* __restrict__ avg_out)
{
    __shared__ f16 ps[2][32][136];
    __shared__ float csh[HH][32];
    const int t = threadIdx.x, lane = t & 63, w = t >> 6;
    const int quad = lane >> 4, m16 = lane & 15;
    const int q0 = blockIdx.x * 32, sl = blockIdx.y, b = blockIdx.z;
    const int ks0 = sl * KSLICE;

    for (int i = t; i < HH*32; i += 256) {
        int hh = i >> 5, qq = i & 31;
        csh[hh][qq] = lse2[((size_t)b*HH + hh)*SQ + q0 + qq];
    }
    __syncthreads();

    float avg_r[KT_IN][16] = {};   // lane-exclusive (q,k) slots, accumulated over h

    for (int hp = 0; hp < 8; ++hp) {
        f32x4 acc[2][2] = {};
        for (int hh2 = 0; hh2 < 2; ++hh2) {
            const int h = hp*2 + hh2;
            half8 bq[2][2];
            #pragma unroll
            for (int nt = 0; nt < 2; ++nt)
                #pragma unroll
                for (int dk = 0; dk < 2; ++dk)
                    bq[nt][dk] = *(const half8*)&Q16[(size_t)((q0 + nt*16 + m16)*BB + b)*EE + h*DD + dk*32 + quad*8];
            const float c01[2] = { csh[h][m16], csh[h][16 + m16] };

            half8 ak[2][2][2], bv[2][4];
            #pragma unroll
            for (int mt = 0; mt < 2; ++mt)
                #pragma unroll
                for (int dk = 0; dk < 2; ++dk)
                    ak[0][mt][dk] = *(const half8*)&K16[(size_t)((ks0 + w*32 + mt*16 + m16)*BB + b)*EE + h*DD + dk*32 + quad*8];
            #pragma unroll
            for (int ks = 0; ks < 4; ++ks)
                bv[0][ks] = *(const half8*)&Vt16[((size_t)b*EE + h*DD + w*16 + m16)*SQ + ks0 + ks*32 + quad*8];

            #pragma unroll
            for (int kt = 0; kt < KT_IN; ++kt) {
                const int cur = kt & 1, nxt = cur ^ 1;
                if (kt + 1 < KT_IN) {   // prefetch next tile's fragments
                    #pragma unroll
                    for (int mt = 0; mt < 2; ++mt)
                        #pragma unroll
                        for (int dk = 0; dk < 2; ++dk)
                            ak[nxt][mt][dk] = *(const half8*)&K16[(size_t)((ks0 + (kt+1)*128 + w*32 + mt*16 + m16)*BB + b)*EE + h*DD + dk*32 + quad*8];
                    #pragma unroll
                    for (int ks = 0; ks < 4; ++ks)
                        bv[nxt][ks] = *(const half8*)&Vt16[((size_t)b*EE + h*DD + w*16 + m16)*SQ + ks0 + (kt+1)*128 + ks*32 + quad*8];
                }
                // S^T = K·Q^T: lane holds 4 consecutive k (rows), fixed q (col)
                #pragma unroll
                for (int mt = 0; mt < 2; ++mt)
                    #pragma unroll
                    for (int nt = 0; nt < 2; ++nt) {
                        f32x4 s = {};
                        s = mfma16(ak[cur][mt][0], bq[nt][0], s);
                        s = mfma16(ak[cur][mt][1], bq[nt][1], s);
                        half4 ph;
                        #pragma unroll
                        for (int r = 0; r < 4; ++r) {
                            float p = __builtin_amdgcn_exp2f(s[r] - c01[nt]);
                            avg_r[kt][mt*8 + nt*4 + r] += p;
                            ph[r] = (f16)p;
                        }
                        *(half4*)&ps[cur][nt*16 + m16][w*32 + mt*16 + quad*4] = ph;
                    }
                __syncthreads();   // ps[cur] complete (double-buffer: 1 barrier/round)
                // PV: ctx[32q x 64d] += P @ V; wave w owns d = w*16..+15
                #pragma unroll
                for (int qt = 0; qt < 2; ++qt) {
                    f32x4 c4 = acc[hh2][qt];
                    #pragma unroll
                    for (int ks = 0; ks < 4; ++ks) {
                        half8 ap = *(half8*)&ps[cur][qt*16 + m16][ks*32 + quad*8];
                        c4 = mfma16(ap, bv[cur][ks], c4);
                    }
                    acc[hh2][qt] = c4;
                }
            }
        }
        // flush 2 heads of ctx partials (fp32)
        #pragma unroll
        for (int hh2 = 0; hh2 < 2; ++hh2)
            #pragma unroll
            for (int qt = 0; qt < 2; ++qt)
                #pragma unroll
                for (int r = 0; r < 4; ++r) {
                    int q = q0 + qt*16 + quad*4 + r;
                    ctxp[(size_t)sl*MM*EE + ((size_t)q*BB + b)*EE + (hp*2 + hh2)*DD + w*16 + m16] = acc[hh2][qt][r];
                }
    }
    // write owned avg tile (float4 stores)
    #pragma unroll
    for (int kt = 0; kt < KT_IN; ++kt)
        #pragma unroll
        for (int mt = 0; mt < 2; ++mt)
            #pragma unroll
            for (int nt = 0; nt < 2; ++nt) {
                int q = q0 + nt*16 + m16;
                int k = ks0 + kt*128 + w*32 + mt*16 + quad*4;
                float4 v = { avg_r[kt][mt*8+nt*4+0]*(1.0f/HH), avg_r[kt][mt*8+nt*4+1]*(1.0f/HH),
                             avg_r[kt][mt*8+nt*4+2]*(1.0f/HH), avg_r[kt][mt*8+nt*4+3]*(1.0f/HH) };
                *(float4*)&avg_out[((size_t)b*SQ + q)*SQ + k] = v;
            }
}

// ---------------- ctx partial reduction: fp32 x NSLICE -> f16 ----------------
__global__ void k_ctx_red(const float* __restrict__ ctxp, f16* __restrict__ ctx16) {
    size_t i = ((size_t)blockIdx.x * 256 + threadIdx.x) * 4;
    float4 s = *(const float4*)&ctxp[i];
    #pragma unroll
    for (int sl = 1; sl < NSLICE; ++sl) {
        float4 v = *(const float4*)&ctxp[(size_t)sl*MM*EE + i];
        s.x += v.x; s.y += v.y; s.z += v.z; s.w += v.w;
    }
    half4 o = {(f16)s.x, (f16)s.y, (f16)s.z, (f16)s.w};
    *(half4*)&ctx16[i] = o;
}

// ---------------- launch ----------------
extern "C" void kernel_launch(void* const* d_in, const int* in_sizes, int n_in,
                              void* d_out, int out_size, void* d_ws, size_t ws_size,
                              hipStream_t stream) {
    const float* query    = (const float*)d_in[0];
    const float* key      = (const float*)d_in[1];
    const float* value    = (const float*)d_in[2];
    const float* q_w      = (const float*)d_in[3];
    const float* q_b      = (const float*)d_in[4];
    const float* k_w      = (const float*)d_in[5];
    const float* k_b      = (const float*)d_in[6];
    const float* v_w      = (const float*)d_in[7];
    const float* v_b      = (const float*)d_in[8];
    const float* o_w_mean = (const float*)d_in[9];
    const float* o_w_lgstd= (const float*)d_in[10];
    const float* eps      = (const float*)d_in[11];
    float* out = (float*)d_out;                  // [S,B,E] fp32
    float* avg = out + (size_t)MM * EE;          // [B,S,S] fp32

    const size_t EWN = (size_t)EE*EE;   // 1M
    const size_t XWN = (size_t)MM*EE;   // 4M
    f16* qw16  = (f16*)d_ws;
    f16* kw16  = qw16 + EWN;
    f16* vw16  = kw16 + EWN;
    f16* ow16  = vw16 + EWN;
    f16* Q16   = ow16 + EWN;
    f16* K16   = Q16  + XWN;
    f16* Vt16  = K16  + XWN;
    f16* ctx16 = Vt16 + XWN;
    float* lse2 = (float*)(ctx16 + XWN);             // B*H*S fp32
    f16* xq16  = (f16*)(lse2 + (size_t)BB*HH*SQ);
    f16* xk16  = xq16 + XWN;
    f16* xv16  = xk16 + XWN;
    // ctxp aliases xq/xk/xv (dead after projections) and extends beyond: NSLICE*16MB
    float* ctxp = (float*)xq16;

    k_elem<<<dim3(XWN/1024, 7), 256, 0, stream>>>(q_w, k_w, v_w, query, key, value,
        o_w_mean, o_w_lgstd, eps, qw16, kw16, vw16, xq16, xk16, xv16, ow16);

    k_gemm_qkv<<<dim3(MM/128, EE/64, 3), 256, 0, stream>>>(
        xq16, qw16, q_b, xk16, kw16, k_b, xv16, vw16, v_b, Q16, K16, Vt16);

    k_attn_l   <<<dim3(SQ/64, HH, BB), 256, 0, stream>>>(Q16, K16, lse2);
    k_attn_main<<<dim3(SQ/32, NSLICE, BB), 256, 0, stream>>>(Q16, K16, Vt16, lse2, ctxp, avg);
    k_ctx_red  <<<XWN/1024, 256, 0, stream>>>(ctxp, ctx16);

    k_gemm_o<<<dim3(MM/128, EE/64), 256, 0, stream>>>(ctx16, ow16, out);
}